// Round 6
// baseline (112.112 us; speedup 1.0000x reference)
//
#include <hip/hip_runtime.h>
#include <hip/hip_bf16.h>

// R18: == R17 structure EXACTLY (2-barrier transposed-logit, all prefetch
// via LDS; measured 41.5-43.0us kernel, dur 111.2, absmax 7.6e-6) with ONE
// isolated change: DISTRIBUTED-LINE BARRIER (release fan-out + line-spread
// arrivals, sleep 8->2) ==
// Theory: 7.3us/barrier (R16) ~= 17.5K cycles >> one MALL round trip. In all
// prior variants 127 blocks poll ONE release word: agent-scope loads can't
// cache, so every poll is a MALL transaction to the same line -> ~127
// serialized services ~= 6-8us. Matches. R9's line-split null was on the
// atomic-RMW barrier (RMW serialization dominated); store-based barrier
// never had distributed polling.
// Fix: one word per 64B line. Arrival: block b stores base[b*16]; block0's
// 128 threads poll 128 DISTINCT lines. Release: block0's 128 threads store
// 128 distinct lines; block b polls only its own. No shared poll lines.
// Phases (R17):
//   entry: xa/xb taps, keys columns -> skc, G taps -> sgx, cw/cb -> LDS
//   A: block's 8 key1 samples -> skv ; partial logits -> plog1  [all blocks]
//   bar1
//   C': reduce 128 partials -> softmax -> kern1 -> w_eff    [REPLICATED]
//   D: key2 samples via w_eff -> skv ; partials -> plog2      [all blocks]
//   bar2
//   F': reduce -> softmax -> kern2 -> composite tables W/Wy/Wx/Wxy
//   G: out = sigmoid(composite convT), taps from sgx           [t<128]
// Ledger (measured): agent acquire/release fences forbidden (R4); cross-block
// data sc1 relaxed-agent only (R8); no dynamic-indexed register arrays (R7);
// no rolled global-load loops (R11); entry prefetch of all static loads
// (R12); keys columns must be LDS-staged, rows were 4-barrier-era (R13/R17);
// NO long-lived prefetch regs across barriers - stage via LDS (R14/R15);
// barrier ~7.3us with shared poll line (R16) -> minimize count AND
// distribute poll lines (this round). Deadlock safety: 128 blocks x 256 thr,
// launch_bounds(256,1), ~46KB LDS -> co-resident on 256 CUs. Barrier state
// (2 x 16KB) zeroed by captured memset node each call.

#define GRID 128

#define LD1(p)     __hip_atomic_load((p), __ATOMIC_RELAXED, __HIP_MEMORY_SCOPE_AGENT)
#define ST1(p, v)  __hip_atomic_store((p), (v), __ATOMIC_RELAXED, __HIP_MEMORY_SCOPE_AGENT)

__device__ __forceinline__ float sigmoidf_(float z) {
    return 1.0f / (1.0f + expf(-z));
}

// base: 4096 words (16KB). arrival[b] at base[b*16] (one 64B line each);
// release[b] at base[2048 + b*16]. No shared poll lines; stores+loads only.
__device__ __forceinline__ void gbar(unsigned* base, int blk, int t) {
    asm volatile("s_waitcnt vmcnt(0)" ::: "memory");   // data sc1 stores visible
    __syncthreads();
    if (t == 0) ST1(base + blk * 16, 1u);              // arrival, own line
    if (blk == 0) {
        if (t < 128) {                                 // 128 distinct lines
            while (LD1(base + t * 16) == 0u)
                __builtin_amdgcn_s_sleep(2);
        }
        __syncthreads();
        if (t < 128) ST1(base + 2048 + t * 16, 1u);    // distributed release
    } else {
        if (t == 0) {                                  // poll OWN line only
            while (LD1(base + 2048 + blk * 16) == 0u)
                __builtin_amdgcn_s_sleep(2);
        }
        __syncthreads();
    }
    asm volatile("" ::: "memory");
    __syncthreads();
}

// entry tap loads for one key stage (2 samples/wave; sample = blk*4+wv+rep*512)
__device__ __forceinline__ void key_prefetch(const float* __restrict__ in,
                                             int mul, int dbl, int blk,
                                             int lane, int wv,
                                             float xa[2], float xb[2]) {
#pragma unroll
    for (int rep = 0; rep < 2; ++rep) {
        int s = blk * 4 + wv + rep * 512;
        int ii = s >> 5, jj = s & 31;
        int qy = (ii * mul) >> 5, qx = (jj * mul) >> 5;
        int by = dbl ? 2 * qy : qy - 1;
        int bx = dbl ? 2 * qx : qx - 1;
        {
            int l = lane;                    // < 64 < 75: always a valid tap
            int ci = l / 25, rm = l % 25, r = rm / 5, cc = rm % 5;
            int y = by + r, x = bx + cc;
            xa[rep] = ((unsigned)y < 1024u && (unsigned)x < 1024u)
                      ? 2.0f * in[ci * 1048576 + y * 1024 + x] - 1.0f : 0.f;
        }
        xb[rep] = 0.f;
        if (lane < 11) {
            int l = lane + 64;
            int ci = l / 25, rm = l % 25, r = rm / 5, cc = rm % 5;
            int y = by + r, x = bx + cc;
            xb[rep] = ((unsigned)y < 1024u && (unsigned)x < 1024u)
                      ? 2.0f * in[ci * 1048576 + y * 1024 + x] - 1.0f : 0.f;
        }
    }
}

// key values from prefetched taps -> skv LDS (24 floats: [c*8 + rep*4 + wv])
__device__ __forceinline__ void key_stage(const float* __restrict__ sw,
                                          const float* __restrict__ sb,
                                          const float xa[2], const float xb[2],
                                          float* __restrict__ skv,
                                          int lane, int wv) {
#pragma unroll
    for (int rep = 0; rep < 2; ++rep) {
        float p0 = xa[rep] * sw[lane];
        float p1 = xa[rep] * sw[75 + lane];
        float p2 = xa[rep] * sw[150 + lane];
        if (lane < 11) {
            p0 += xb[rep] * sw[64 + lane];
            p1 += xb[rep] * sw[139 + lane];
            p2 += xb[rep] * sw[214 + lane];
        }
#pragma unroll
        for (int off = 32; off > 0; off >>= 1) {
            p0 += __shfl_xor(p0, off, 64);
            p1 += __shfl_xor(p1, off, 64);
            p2 += __shfl_xor(p2, off, 64);
        }
        if (lane == 0) {
            skv[0 * 8 + rep * 4 + wv] = sigmoidf_(p0 + sb[0]);
            skv[1 * 8 + rep * 4 + wv] = sigmoidf_(p1 + sb[1]);
            skv[2 * 8 + rep * 4 + wv] = sigmoidf_(p2 + sb[2]);
        }
    }
}

// softmax over slog[0..99] (LDS) -> satt (LDS); runs in every block
__device__ __forceinline__ void softmax_lds(const float* __restrict__ slog,
                                            float* __restrict__ satt,
                                            int lane, int wv) {
    if (wv == 0) {
        float v1 = slog[lane];
        float v2 = (lane + 64 < 100) ? slog[lane + 64] : -3.4e38f;
        float mx = fmaxf(v1, v2);
#pragma unroll
        for (int off = 32; off > 0; off >>= 1) mx = fmaxf(mx, __shfl_xor(mx, off, 64));
        float e1 = expf(v1 - mx);
        float e2 = (lane + 64 < 100) ? expf(v2 - mx) : 0.f;
        float s = e1 + e2;
#pragma unroll
        for (int off = 32; off > 0; off >>= 1) s += __shfl_xor(s, off, 64);
        float inv = 1.0f / s;
        satt[lane] = e1 * inv;
        if (lane + 64 < 100) satt[lane + 64] = e2 * inv;
    }
    __syncthreads();
}

__global__ __launch_bounds__(256, 1) void k_fused(
    const float* __restrict__ in, const float* __restrict__ cw,
    const float* __restrict__ cb, const float* __restrict__ keys,
    const float* __restrict__ vals, float* __restrict__ out,
    float* __restrict__ ws, unsigned* __restrict__ ctr)
{
    __shared__ float smem[11380];
    float* sk1  = smem;          // 225  kern1 (persists C'->F')
    float* sk2  = smem + 232;    // 225  kern2
    float* satt = smem + 464;    // 100  softmax
    float* sw   = smem + 568;    // 225  conv weights, then w_eff
    float* sb   = smem + 800;    // 3    bias
    float* sW   = smem + 808;    // 1521 composite W [(ci*3+o)*169 + e*13+f]
    float* sWy  = smem + 2332;   // 117
    float* sWx  = smem + 2452;   // 117
    float* sWxy = smem + 2572;   // 9
    float* skv  = smem + 2584;   // 24   block's key samples [c*8+rep*4+wv]
    float* slog = smem + 2608;   // 128  reduced logits
    float* skc  = smem + 2736;   // 2500 keys cols [t*25 + c*8+r*4+w], pad 25
    float* sgx  = smem + 5236;   // 6144 G taps [((ch*4+k)*4+l)*128 + j]

    float* plog1 = ws;           // [128 blocks][128 stride], 100 used
    float* plog2 = ws + 16384;

    const int t = threadIdx.x, lane = t & 63, wv = t >> 6;
    const int blk = blockIdx.x;

    // ---- entry prefetch: key-stage taps (only xa2/xb2 live across bar1) ----
    float xa1[2], xb1[2], xa2[2], xb2[2];
    key_prefetch(in, 510, 1, blk, lane, wv, xa1, xb1);
    key_prefetch(in, 1022, 0, blk, lane, wv, xa2, xb2);

    // ---- entry: keys columns for this block's 8 samples -> LDS (R14 fix) ----
    if (t < 100) {
        const float* kr = keys + t * 3072 + blk * 4;
#pragma unroll
        for (int c = 0; c < 3; ++c)
#pragma unroll
            for (int r = 0; r < 2; ++r) {
                float4 kk = *reinterpret_cast<const float4*>(kr + c * 1024 + r * 512);
                int o = t * 25 + c * 8 + r * 4;
                skc[o]     = kk.x;
                skc[o + 1] = kk.y;
                skc[o + 2] = kk.z;
                skc[o + 3] = kk.w;
            }
    }

    // ---- entry: stage G taps into LDS (registers die here; R14 lesson) ----
    const int j = t & 127, h = t >> 7;
    const int R = (blk * 4093) >> 7;
    const int C = (j * 4093) >> 7;
    const int ybase = (R + 6) >> 2, r0 = (R + 6) & 3, nk = (r0 == 0) ? 4 : 3;
    const int xbase = (C + 6) >> 2, f0 = (C + 6) & 3, nl = (f0 == 0) ? 4 : 3;
#pragma unroll
    for (int k = 0; k < 4; ++k) {
        int iy = ybase - k;
#pragma unroll
        for (int lh = 0; lh < 2; ++lh) {
            int l = h * 2 + lh;
            int ix = xbase - l;
            bool ok = ((unsigned)iy < 1024u) && ((unsigned)ix < 1024u)
                      && (k < nk) && (l < nl);
            int off = iy * 1024 + ix;
            float v0 = ok ? 2.0f * in[off] - 1.0f : 0.f;
            float v1 = ok ? 2.0f * in[1048576 + off] - 1.0f : 0.f;
            float v2 = ok ? 2.0f * in[2097152 + off] - 1.0f : 0.f;
            int si = (k * 4 + l) * 128 + j;
            sgx[si]        = v0;
            sgx[2048 + si] = v1;
            sgx[4096 + si] = v2;
        }
    }

    if (t < 225) sw[t] = cw[t];
    if (t < 3)   sb[t] = cb[t];
    __syncthreads();

    // ---- A: key1 samples -> skv, partial logits -> plog1 (all blocks) ----
    key_stage(sw, sb, xa1, xb1, skv, lane, wv);
    __syncthreads();
    if (t < 100) {
        float s = 0.f;
        const float* kc = skc + t * 25;
#pragma unroll
        for (int i = 0; i < 24; ++i) s += kc[i] * skv[i];
        ST1(plog1 + blk * 128 + t, s);
    }
    gbar(ctr, blk, t);

    // ---- C' (replicated): reduce partials -> softmax -> kern1 -> w_eff ----
    if (t < 100) {
        const float* p = plog1 + t;
        float s0 = 0.f, s1 = 0.f, s2 = 0.f, s3 = 0.f;
#pragma unroll
        for (int b = 0; b < 32; ++b) {
            s0 += LD1(p + (4 * b + 0) * 128);
            s1 += LD1(p + (4 * b + 1) * 128);
            s2 += LD1(p + (4 * b + 2) * 128);
            s3 += LD1(p + (4 * b + 3) * 128);
        }
        slog[t] = (s0 + s1) + (s2 + s3);
    }
    __syncthreads();
    softmax_lds(slog, satt, lane, wv);
    if (t < 225) {
        float s = 0.f;
#pragma unroll
        for (int n = 0; n < 100; ++n) s += vals[n * 225 + t] * satt[n];
        sk1[t] = s;
    }
    __syncthreads();
    if (t < 225) {   // w_eff[co][ci][a][bb] = conv(convT(.,kern1)) composite
        int co = t / 75, rem = t % 75, ci = rem / 25, a = (rem % 25) / 5, bb = rem % 5;
        float s = 0.f;
#pragma unroll
        for (int c = 0; c < 5; ++c) {
            int u = c + 2 * a - 4;
            if ((unsigned)u >= 5u) continue;
#pragma unroll
            for (int d = 0; d < 5; ++d) {
                int v = d + 2 * bb - 4;
                if ((unsigned)v >= 5u) continue;
#pragma unroll
                for (int cm = 0; cm < 3; ++cm)
                    s += sk1[ci * 75 + cm * 25 + c * 5 + d] * cw[co * 75 + cm * 25 + u * 5 + v];
            }
        }
        sw[t] = s;    // nobody reads old sw in this phase
    }
    __syncthreads();

    // ---- D: key2 samples via w_eff -> skv, partials -> plog2 ----
    key_stage(sw, sb, xa2, xb2, skv, lane, wv);
    __syncthreads();
    if (t < 100) {
        float s = 0.f;
        const float* kc = skc + t * 25;
#pragma unroll
        for (int i = 0; i < 24; ++i) s += kc[i] * skv[i];
        ST1(plog2 + blk * 128 + t, s);
    }
    gbar(ctr + 4096, blk, t);

    // ---- F' (replicated): reduce -> softmax -> kern2 -> composite tables ----
    if (t < 100) {
        const float* p = plog2 + t;
        float s0 = 0.f, s1 = 0.f, s2 = 0.f, s3 = 0.f;
#pragma unroll
        for (int b = 0; b < 32; ++b) {
            s0 += LD1(p + (4 * b + 0) * 128);
            s1 += LD1(p + (4 * b + 1) * 128);
            s2 += LD1(p + (4 * b + 2) * 128);
            s3 += LD1(p + (4 * b + 3) * 128);
        }
        slog[t] = (s0 + s1) + (s2 + s3);
    }
    __syncthreads();
    softmax_lds(slog, satt, lane, wv);
    if (t < 225) {
        float s = 0.f;
#pragma unroll
        for (int n = 0; n < 100; ++n) s += vals[n * 225 + t] * satt[n];
        sk2[t] = s;
    }
    __syncthreads();
    for (int idx = t; idx < 1521; idx += 256) {   // W
        int ci = idx / 507, rem = idx % 507, o = rem / 169;
        int ef = rem % 169, e = ef / 13, f = ef % 13;
        float s = 0.f;
#pragma unroll
        for (int c = 0; c < 5; ++c) {
            int a = e - 2 * c;
            if ((unsigned)a >= 5u) continue;
#pragma unroll
            for (int d = 0; d < 5; ++d) {
                int b2 = f - 2 * d;
                if ((unsigned)b2 >= 5u) continue;
#pragma unroll
                for (int cm = 0; cm < 3; ++cm)
                    s += sk1[ci * 75 + cm * 25 + c * 5 + d] * sk2[cm * 75 + o * 25 + a * 5 + b2];
            }
        }
        sW[idx] = s;
    }
    if (t < 117) {   // Wy: phantom out1-row (c=1 -> oy1=-1), a=4
        int ci = t / 39, o = (t % 39) / 13, f = t % 13;
        float s = 0.f;
#pragma unroll
        for (int d = 0; d < 5; ++d) {
            int b2 = f - 2 * d;
            if ((unsigned)b2 >= 5u) continue;
#pragma unroll
            for (int cm = 0; cm < 3; ++cm)
                s += sk1[ci * 75 + cm * 25 + 5 + d] * sk2[cm * 75 + o * 25 + 20 + b2];
        }
        sWy[(ci * 3 + o) * 13 + f] = s;
    }
    if (t >= 128 && t < 245) {   // Wx: phantom out1-col (d=1 -> ox1=-1), b=4
        int q = t - 128;
        int ci = q / 39, o = (q % 39) / 13, e = q % 13;
        float s = 0.f;
#pragma unroll
        for (int c = 0; c < 5; ++c) {
            int a = e - 2 * c;
            if ((unsigned)a >= 5u) continue;
#pragma unroll
            for (int cm = 0; cm < 3; ++cm)
                s += sk1[ci * 75 + cm * 25 + c * 5 + 1] * sk2[cm * 75 + o * 25 + a * 5 + 4];
        }
        sWx[(ci * 3 + o) * 13 + e] = s;
    }
    if (t >= 246 && t < 255) {   // Wxy overlap
        int q = t - 246;
        int ci = q / 3, o = q % 3;
        float s = 0.f;
#pragma unroll
        for (int cm = 0; cm < 3; ++cm)
            s += sk1[ci * 75 + cm * 25 + 5 + 1] * sk2[cm * 75 + o * 25 + 20 + 4];
        sWxy[ci * 3 + o] = s;
    }
    __syncthreads();

    // ---- G: final sampled composite convT + sigmoid (taps + tables in LDS) ----
    if (t < 128) {
        float a0 = 0.f, a1 = 0.f, a2 = 0.f;
#pragma unroll
        for (int k = 0; k < 4; ++k) {
            if (k < nk) {
                int e = r0 + 4 * k;
#pragma unroll
                for (int l = 0; l < 4; ++l) {
                    if (l < nl) {
                        int f = f0 + 4 * l;
                        int wi = e * 13 + f;
                        int si = (k * 4 + l) * 128 + j;
                        float x0 = sgx[si], x1 = sgx[2048 + si], x2 = sgx[4096 + si];
                        a0 += x0 * sW[wi]       + x1 * sW[507 + wi]  + x2 * sW[1014 + wi];
                        a1 += x0 * sW[169 + wi] + x1 * sW[676 + wi]  + x2 * sW[1183 + wi];
                        a2 += x0 * sW[338 + wi] + x1 * sW[845 + wi]  + x2 * sW[1352 + wi];
                    }
                }
            }
        }
        if (R == 0) {
            for (int l = 0; l < nl; ++l) {
                int ix = xbase - l;
                if ((unsigned)ix >= 1024u) continue;
                int f = f0 + 4 * l;
                float x0 = 2.0f * in[ix] - 1.0f;
                float x1 = 2.0f * in[1048576 + ix] - 1.0f;
                float x2 = 2.0f * in[2097152 + ix] - 1.0f;
                a0 -= x0 * sWy[f]      + x1 * sWy[39 + f] + x2 * sWy[78 + f];
                a1 -= x0 * sWy[13 + f] + x1 * sWy[52 + f] + x2 * sWy[91 + f];
                a2 -= x0 * sWy[26 + f] + x1 * sWy[65 + f] + x2 * sWy[104 + f];
            }
        }
        if (C == 0) {
            for (int k = 0; k < nk; ++k) {
                int iy = ybase - k;
                if ((unsigned)iy >= 1024u) continue;
                int e = r0 + 4 * k;
                int off = iy * 1024;
                float x0 = 2.0f * in[off] - 1.0f;
                float x1 = 2.0f * in[1048576 + off] - 1.0f;
                float x2 = 2.0f * in[2097152 + off] - 1.0f;
                a0 -= x0 * sWx[e]      + x1 * sWx[39 + e] + x2 * sWx[78 + e];
                a1 -= x0 * sWx[13 + e] + x1 * sWx[52 + e] + x2 * sWx[91 + e];
                a2 -= x0 * sWx[26 + e] + x1 * sWx[65 + e] + x2 * sWx[104 + e];
            }
        }
        if (R == 0 && C == 0) {
            float x0 = 2.0f * in[0] - 1.0f;
            float x1 = 2.0f * in[1048576] - 1.0f;
            float x2 = 2.0f * in[2097152] - 1.0f;
            a0 += x0 * sWxy[0] + x1 * sWxy[3] + x2 * sWxy[6];
            a1 += x0 * sWxy[1] + x1 * sWxy[4] + x2 * sWxy[7];
            a2 += x0 * sWxy[2] + x1 * sWxy[5] + x2 * sWxy[8];
        }
        int T = blk * 128 + j;
        out[T]             = sigmoidf_(a0);
        out[16384 + T]     = sigmoidf_(a1);
        out[2 * 16384 + T] = sigmoidf_(a2);
    }
}

extern "C" void kernel_launch(void* const* d_in, const int* in_sizes, int n_in,
                              void* d_out, int out_size, void* d_ws, size_t ws_size,
                              hipStream_t stream) {
    const float* in   = (const float*)d_in[0];   // [3,1024,1024]
    const float* cw   = (const float*)d_in[1];   // [3,3,5,5]
    const float* cb   = (const float*)d_in[2];   // [3]
    const float* keys = (const float*)d_in[3];   // [100,3072]
    const float* vals = (const float*)d_in[4];   // [100,225]
    float* out = (float*)d_out;                  // [3,128,128] fp32

    unsigned* ctr = (unsigned*)d_ws;             // 2 barriers x 16KB, line-spread
    float* wsf = (float*)((char*)d_ws + 32768);  // float scratch: 2 x 16384 plog

    hipMemsetAsync(d_ws, 0, 32768, stream);      // zero barrier state
    k_fused<<<GRID, 256, 0, stream>>>(in, cw, cb, keys, vals, out, wsf, ctr);
}